// Round 1
// baseline (483.652 us; speedup 1.0000x reference)
//
#include <hip/hip_runtime.h>

#define N_NODES 100000
#define N_EDGES 1600000

// ---------------- degree / dinv ----------------

__global__ void k_init_deg(float* __restrict__ deg, int n) {
    int i = blockIdx.x * blockDim.x + threadIdx.x;
    if (i < n) deg[i] = 1.0f;   // self loop contributes 1 to every node
}

__global__ void k_count_deg(const int* __restrict__ dst, float* __restrict__ deg, int e) {
    int i = blockIdx.x * blockDim.x + threadIdx.x;
    if (i < e) atomicAdd(&deg[dst[i]], 1.0f);
}

__global__ void k_dinv(float* __restrict__ deg, int n) {
    int i = blockIdx.x * blockDim.x + threadIdx.x;
    if (i < n) deg[i] = rsqrtf(deg[i]);   // deg >= 1 always (self loop)
}

// ---------------- per-layer kernels ----------------

// hn[i,c] = (act[i,:] @ W[:,c]) * dinv[i]
template <int CIN, int COUT>
__global__ void k_transform(const float* __restrict__ act, const float* __restrict__ W,
                            const float* __restrict__ dinv, float* __restrict__ hn, int n) {
    int t = blockIdx.x * blockDim.x + threadIdx.x;
    if (t >= n * COUT) return;
    int i = t / COUT;
    int c = t - i * COUT;
    float s = 0.0f;
#pragma unroll
    for (int k = 0; k < CIN; ++k) s += act[i * CIN + k] * W[k * COUT + c];
    hn[t] = s * dinv[i];
}

__global__ void k_zero(float* __restrict__ p, int n) {
    int i = blockIdx.x * blockDim.x + threadIdx.x;
    if (i < n) p[i] = 0.0f;
}

// acc[dst,c] += hn[src,c] for every edge
template <int C>
__global__ void k_scatter(const int* __restrict__ src, const int* __restrict__ dst,
                          const float* __restrict__ hn, float* __restrict__ acc, int e) {
    int t = blockIdx.x * blockDim.x + threadIdx.x;
    if (t >= e * C) return;
    int ei = t / C;           // C is a power of two -> shifts
    int c  = t - ei * C;
    int s = src[ei];
    int d = dst[ei];
    atomicAdd(&acc[d * C + c], hn[s * C + c]);
}

// act[i,c] = relu(dinv[i]*(acc[i,c] + hn[i,c]) + b[c])   (in place into acc)
template <int C>
__global__ void k_finalize(const float* __restrict__ hn, float* __restrict__ acc,
                           const float* __restrict__ dinv, const float* __restrict__ b, int n) {
    int t = blockIdx.x * blockDim.x + threadIdx.x;
    if (t >= n * C) return;
    int i = t / C;
    int c = t - i * C;
    float v = dinv[i] * (acc[t] + hn[t]) + b[c];
    acc[t] = v > 0.0f ? v : 0.0f;
}

// fused layer-3 finalize + final 8->1 linear
__global__ void k_final(const float* __restrict__ hn, const float* __restrict__ acc,
                        const float* __restrict__ dinv, const float* __restrict__ b3,
                        const float* __restrict__ Wf, const float* __restrict__ bf,
                        float* __restrict__ out, int n) {
    int i = blockIdx.x * blockDim.x + threadIdx.x;
    if (i >= n) return;
    float di = dinv[i];
    float s = bf[0];
#pragma unroll
    for (int c = 0; c < 8; ++c) {
        float v = di * (acc[i * 8 + c] + hn[i * 8 + c]) + b3[c];
        s += (v > 0.0f ? v : 0.0f) * Wf[c];
    }
    out[i] = s;
}

// ---------------- launch ----------------

static inline int cdiv(int a, int b) { return (a + b - 1) / b; }

extern "C" void kernel_launch(void* const* d_in, const int* in_sizes, int n_in,
                              void* d_out, int out_size, void* d_ws, size_t ws_size,
                              hipStream_t stream) {
    const float* x  = (const float*)d_in[0];
    const int*   ei = (const int*)d_in[1];
    const float* W1 = (const float*)d_in[2];
    const float* b1 = (const float*)d_in[3];
    const float* W2 = (const float*)d_in[4];
    const float* b2 = (const float*)d_in[5];
    const float* W3 = (const float*)d_in[6];
    const float* b3 = (const float*)d_in[7];
    const float* Wf = (const float*)d_in[8];
    const float* bf = (const float*)d_in[9];
    float* out = (float*)d_out;

    const int n = N_NODES;
    const int e = N_EDGES;
    const int* src = ei;
    const int* dst = ei + e;

    // workspace layout (floats): dinv[n] | bufA[n*32] | bufB[n*32]
    float* dinv = (float*)d_ws;
    float* bufA = dinv + n;          // hn buffer
    float* bufB = bufA + n * 32;     // acc / activation buffer

    const int B = 256;

    // degree -> dinv (once, reused by all 3 layers)
    k_init_deg<<<cdiv(n, B), B, 0, stream>>>(dinv, n);
    k_count_deg<<<cdiv(e, B), B, 0, stream>>>(dst, dinv, e);
    k_dinv<<<cdiv(n, B), B, 0, stream>>>(dinv, n);

    // ---- layer 1: x[ n,3 ] -> 32 ----
    k_transform<3, 32><<<cdiv(n * 32, B), B, 0, stream>>>(x, W1, dinv, bufA, n);
    k_zero<<<cdiv(n * 32, B), B, 0, stream>>>(bufB, n * 32);
    k_scatter<32><<<cdiv(e * 32, B), B, 0, stream>>>(src, dst, bufA, bufB, e);
    k_finalize<32><<<cdiv(n * 32, B), B, 0, stream>>>(bufA, bufB, dinv, b1, n);

    // ---- layer 2: 32 -> 16 ----
    k_transform<32, 16><<<cdiv(n * 16, B), B, 0, stream>>>(bufB, W2, dinv, bufA, n);
    k_zero<<<cdiv(n * 16, B), B, 0, stream>>>(bufB, n * 16);
    k_scatter<16><<<cdiv(e * 16, B), B, 0, stream>>>(src, dst, bufA, bufB, e);
    k_finalize<16><<<cdiv(n * 16, B), B, 0, stream>>>(bufA, bufB, dinv, b2, n);

    // ---- layer 3: 16 -> 8 ----
    k_transform<16, 8><<<cdiv(n * 8, B), B, 0, stream>>>(bufB, W3, dinv, bufA, n);
    k_zero<<<cdiv(n * 8, B), B, 0, stream>>>(bufB, n * 8);
    k_scatter<8><<<cdiv(e * 8, B), B, 0, stream>>>(src, dst, bufA, bufB, e);

    // ---- fused layer-3 finalize + final linear 8 -> 1 ----
    k_final<<<cdiv(n, B), B, 0, stream>>>(bufA, bufB, dinv, b3, Wf, bf, out, n);
}

// Round 2
// 313.180 us; speedup vs baseline: 1.5443x; 1.5443x over previous
//
#include <hip/hip_runtime.h>

#define N_NODES 100000
#define N_EDGES 1600000
#define SCAN_BS 1024

static inline int cdiv(int a, int b) { return (a + b - 1) / b; }

// ---------------- CSR build ----------------

__global__ void k_zero_int(int* __restrict__ p, int n) {
    int i = blockIdx.x * blockDim.x + threadIdx.x;
    if (i < n) p[i] = 0;
}

__global__ void k_hist(const int* __restrict__ dst, int* __restrict__ hist, int e) {
    int i = blockIdx.x * blockDim.x + threadIdx.x;
    if (i < e) atomicAdd(&hist[dst[i]], 1);
}

// dinv[i] = rsqrt(in_degree + 1)   (self loop adds 1; always >= 1)
__global__ void k_dinv(const int* __restrict__ hist, float* __restrict__ dinv, int n) {
    int i = blockIdx.x * blockDim.x + threadIdx.x;
    if (i < n) dinv[i] = rsqrtf((float)(hist[i] + 1));
}

// per-block exclusive scan of hist -> rowptr, block totals -> sums
__global__ void k_scan_block(const int* __restrict__ hist, int* __restrict__ rowptr,
                             int* __restrict__ sums, int n) {
    __shared__ int tmp[SCAN_BS];
    int t = threadIdx.x, b = blockIdx.x;
    int i = b * SCAN_BS + t;
    int v = (i < n) ? hist[i] : 0;
    tmp[t] = v;
    __syncthreads();
    for (int off = 1; off < SCAN_BS; off <<= 1) {
        int x = (t >= off) ? tmp[t - off] : 0;
        __syncthreads();
        tmp[t] += x;
        __syncthreads();
    }
    if (i <= n) rowptr[i] = tmp[t] - v;          // exclusive
    if (t == SCAN_BS - 1) sums[b] = tmp[t];      // block total
}

// single-block exclusive scan of block sums (nb <= 128)
__global__ void k_scan_sums(int* __restrict__ sums, int nb) {
    __shared__ int tmp[128];
    int t = threadIdx.x;
    int v = (t < nb) ? sums[t] : 0;
    tmp[t] = v;
    __syncthreads();
    for (int off = 1; off < 128; off <<= 1) {
        int x = (t >= off) ? tmp[t - off] : 0;
        __syncthreads();
        tmp[t] += x;
        __syncthreads();
    }
    if (t < nb) sums[t] = tmp[t] - v;            // exclusive
}

// add block offsets; also seed the fill cursor
__global__ void k_scan_add(int* __restrict__ rowptr, const int* __restrict__ sums,
                           int* __restrict__ cursor, int n) {
    int i = blockIdx.x * blockDim.x + threadIdx.x;
    if (i <= n) {
        int v = rowptr[i] + sums[i >> 10];
        rowptr[i] = v;
        if (i < n) cursor[i] = v;
    }
}

// counting-sort fill: srcs segment for each dst
__global__ void k_fill(const int* __restrict__ src, const int* __restrict__ dst,
                       int* __restrict__ cursor, int* __restrict__ srcs, int e) {
    int i = blockIdx.x * blockDim.x + threadIdx.x;
    if (i < e) {
        int d = dst[i];
        int p = atomicAdd(&cursor[d], 1);
        srcs[p] = src[i];
    }
}

// ---------------- per-layer kernels ----------------

// hn[i,:] = (act[i,:] @ W) * dinv[i]
template <int CIN, int COUT>
__global__ void k_transform(const float* __restrict__ act, const float* __restrict__ W,
                            const float* __restrict__ dinv, float* __restrict__ hn, int n) {
    int i = blockIdx.x * blockDim.x + threadIdx.x;
    if (i >= n) return;
    float row[CIN];
    if constexpr (CIN % 4 == 0) {
        const float4* a4 = (const float4*)(act + (size_t)i * CIN);
#pragma unroll
        for (int k = 0; k < CIN / 4; ++k) {
            float4 v = a4[k];
            row[4 * k] = v.x; row[4 * k + 1] = v.y; row[4 * k + 2] = v.z; row[4 * k + 3] = v.w;
        }
    } else {
#pragma unroll
        for (int k = 0; k < CIN; ++k) row[k] = act[(size_t)i * CIN + k];
    }
    float di = dinv[i];
    float o[COUT];
#pragma unroll
    for (int c = 0; c < COUT; ++c) {
        float s = 0.0f;
#pragma unroll
        for (int k = 0; k < CIN; ++k) s += row[k] * W[k * COUT + c];
        o[c] = s * di;
    }
    float4* h4 = (float4*)(hn + (size_t)i * COUT);
#pragma unroll
    for (int c = 0; c < COUT / 4; ++c) {
        float4 v; v.x = o[4 * c]; v.y = o[4 * c + 1]; v.z = o[4 * c + 2]; v.w = o[4 * c + 3];
        h4[c] = v;
    }
}

// gather + finalize: act[i,c] = relu(dinv[i]*(hn[i,c] + sum_{s in N(i)} hn[s,c]) + b[c])
// one thread per (node, float4 quad)
template <int C>
__global__ void k_gather(const int* __restrict__ rowptr, const int* __restrict__ srcs,
                         const float* __restrict__ hn, const float* __restrict__ dinv,
                         const float* __restrict__ b, float* __restrict__ act, int n) {
    constexpr int Q = C / 4;
    int t = blockIdx.x * blockDim.x + threadIdx.x;
    if (t >= n * Q) return;
    int i = t / Q;
    int q = t - i * Q;
    const float4* hn4 = (const float4*)hn;
    float4 acc = hn4[(size_t)i * Q + q];          // self loop
    int r0 = rowptr[i], r1 = rowptr[i + 1];
    for (int j = r0; j < r1; ++j) {
        int s = srcs[j];
        float4 v = hn4[(size_t)s * Q + q];
        acc.x += v.x; acc.y += v.y; acc.z += v.z; acc.w += v.w;
    }
    float di = dinv[i];
    float4 bb = ((const float4*)b)[q];
    float4 o;
    o.x = fmaxf(di * acc.x + bb.x, 0.0f);
    o.y = fmaxf(di * acc.y + bb.y, 0.0f);
    o.z = fmaxf(di * acc.z + bb.z, 0.0f);
    o.w = fmaxf(di * acc.w + bb.w, 0.0f);
    ((float4*)act)[(size_t)i * Q + q] = o;
}

// layer-3 gather (C=8) fused with finalize + final 8->1 linear
__global__ void k_gather_final(const int* __restrict__ rowptr, const int* __restrict__ srcs,
                               const float* __restrict__ hn, const float* __restrict__ dinv,
                               const float* __restrict__ b3, const float* __restrict__ Wf,
                               const float* __restrict__ bf, float* __restrict__ out, int n) {
    int i = blockIdx.x * blockDim.x + threadIdx.x;
    if (i >= n) return;
    const float4* hn4 = (const float4*)hn;
    float4 a0 = hn4[(size_t)i * 2];
    float4 a1 = hn4[(size_t)i * 2 + 1];
    int r0 = rowptr[i], r1 = rowptr[i + 1];
    for (int j = r0; j < r1; ++j) {
        int s = srcs[j];
        float4 v0 = hn4[(size_t)s * 2];
        float4 v1 = hn4[(size_t)s * 2 + 1];
        a0.x += v0.x; a0.y += v0.y; a0.z += v0.z; a0.w += v0.w;
        a1.x += v1.x; a1.y += v1.y; a1.z += v1.z; a1.w += v1.w;
    }
    float di = dinv[i];
    float4 bb0 = ((const float4*)b3)[0], bb1 = ((const float4*)b3)[1];
    float4 w0 = ((const float4*)Wf)[0],  w1 = ((const float4*)Wf)[1];
    float s = bf[0];
    s += fmaxf(di * a0.x + bb0.x, 0.0f) * w0.x;
    s += fmaxf(di * a0.y + bb0.y, 0.0f) * w0.y;
    s += fmaxf(di * a0.z + bb0.z, 0.0f) * w0.z;
    s += fmaxf(di * a0.w + bb0.w, 0.0f) * w0.w;
    s += fmaxf(di * a1.x + bb1.x, 0.0f) * w1.x;
    s += fmaxf(di * a1.y + bb1.y, 0.0f) * w1.y;
    s += fmaxf(di * a1.z + bb1.z, 0.0f) * w1.z;
    s += fmaxf(di * a1.w + bb1.w, 0.0f) * w1.w;
    out[i] = s;
}

// ---------------- launch ----------------

extern "C" void kernel_launch(void* const* d_in, const int* in_sizes, int n_in,
                              void* d_out, int out_size, void* d_ws, size_t ws_size,
                              hipStream_t stream) {
    const float* x  = (const float*)d_in[0];
    const int*   ei = (const int*)d_in[1];
    const float* W1 = (const float*)d_in[2];
    const float* b1 = (const float*)d_in[3];
    const float* W2 = (const float*)d_in[4];
    const float* b2 = (const float*)d_in[5];
    const float* W3 = (const float*)d_in[6];
    const float* b3 = (const float*)d_in[7];
    const float* Wf = (const float*)d_in[8];
    const float* bf = (const float*)d_in[9];
    float* out = (float*)d_out;

    const int n = N_NODES;
    const int e = N_EDGES;
    const int* src = ei;
    const int* dst = ei + e;

    // workspace layout:
    // floats: bufA[n*32] | bufB[n*32] | dinv[n]
    // ints:   srcs[e] | rowptr[n+1] | cursor[n] | hist[n] | sums[128]
    float* bufA  = (float*)d_ws;            // hn buffer
    float* bufB  = bufA + (size_t)n * 32;   // activation buffer
    float* dinv  = bufB + (size_t)n * 32;
    int*   srcs   = (int*)(dinv + n);
    int*   rowptr = srcs + e;
    int*   cursor = rowptr + (n + 1);
    int*   hist   = cursor + n;
    int*   sums   = hist + n;

    const int B = 256;
    const int nScanBlocks = cdiv(n, SCAN_BS);   // 98

    // ---- CSR build + dinv ----
    k_zero_int<<<cdiv(n, B), B, 0, stream>>>(hist, n);
    k_hist<<<cdiv(e, B), B, 0, stream>>>(dst, hist, e);
    k_dinv<<<cdiv(n, B), B, 0, stream>>>(hist, dinv, n);
    k_scan_block<<<nScanBlocks, SCAN_BS, 0, stream>>>(hist, rowptr, sums, n);
    k_scan_sums<<<1, 128, 0, stream>>>(sums, nScanBlocks);
    k_scan_add<<<cdiv(n + 1, B), B, 0, stream>>>(rowptr, sums, cursor, n);
    k_fill<<<cdiv(e, B), B, 0, stream>>>(src, dst, cursor, srcs, e);

    // ---- layer 1: 3 -> 32 ----
    k_transform<3, 32><<<cdiv(n, B), B, 0, stream>>>(x, W1, dinv, bufA, n);
    k_gather<32><<<cdiv(n * 8, B), B, 0, stream>>>(rowptr, srcs, bufA, dinv, b1, bufB, n);

    // ---- layer 2: 32 -> 16 ----
    k_transform<32, 16><<<cdiv(n, B), B, 0, stream>>>(bufB, W2, dinv, bufA, n);
    k_gather<16><<<cdiv(n * 4, B), B, 0, stream>>>(rowptr, srcs, bufA, dinv, b2, bufB, n);

    // ---- layer 3: 16 -> 8 + final linear ----
    k_transform<16, 8><<<cdiv(n, B), B, 0, stream>>>(bufB, W3, dinv, bufA, n);
    k_gather_final<<<cdiv(n, B), B, 0, stream>>>(rowptr, srcs, bufA, dinv, b3, Wf, bf, out, n);
}

// Round 3
// 288.200 us; speedup vs baseline: 1.6782x; 1.0867x over previous
//
#include <hip/hip_runtime.h>

#define N_NODES 100000
#define N_EDGES 1600000
#define SCAN_BS 1024

static inline int cdiv(int a, int b) { return (a + b - 1) / b; }

__device__ inline float4 f4add(float4 a, float4 b) {
    a.x += b.x; a.y += b.y; a.z += b.z; a.w += b.w; return a;
}
__device__ inline float4 f4fma(float s, float4 w, float4 a) {
    a.x = fmaf(s, w.x, a.x); a.y = fmaf(s, w.y, a.y);
    a.z = fmaf(s, w.z, a.z); a.w = fmaf(s, w.w, a.w); return a;
}
// relu(di*a + b)
__device__ inline float4 f4relu(float di, float4 a, float4 b) {
    float4 o;
    o.x = fmaxf(fmaf(di, a.x, b.x), 0.0f);
    o.y = fmaxf(fmaf(di, a.y, b.y), 0.0f);
    o.z = fmaxf(fmaf(di, a.z, b.z), 0.0f);
    o.w = fmaxf(fmaf(di, a.w, b.w), 0.0f);
    return o;
}

// ---------------- CSR build ----------------

__global__ void k_zero_int(int* __restrict__ p, int n) {
    int i = blockIdx.x * blockDim.x + threadIdx.x;
    if (i < n) p[i] = 0;
}

__global__ void k_hist(const int* __restrict__ dst, int* __restrict__ hist, int e) {
    int i = blockIdx.x * blockDim.x + threadIdx.x;
    if (i < e) atomicAdd(&hist[__builtin_nontemporal_load(&dst[i])], 1);
}

// dinv[i] = rsqrt(deg+1); xd[i] = {x[i,:3]*dinv, 0}
__global__ void k_dinv_xd(const int* __restrict__ hist, const float* __restrict__ x,
                          float* __restrict__ dinv, float4* __restrict__ xd, int n) {
    int i = blockIdx.x * blockDim.x + threadIdx.x;
    if (i >= n) return;
    float di = rsqrtf((float)(hist[i] + 1));
    dinv[i] = di;
    float4 v;
    v.x = x[3 * i] * di; v.y = x[3 * i + 1] * di; v.z = x[3 * i + 2] * di; v.w = 0.0f;
    xd[i] = v;
}

__global__ void k_scan_block(const int* __restrict__ hist, int* __restrict__ rowptr,
                             int* __restrict__ sums, int n) {
    __shared__ int tmp[SCAN_BS];
    int t = threadIdx.x, b = blockIdx.x;
    int i = b * SCAN_BS + t;
    int v = (i < n) ? hist[i] : 0;
    tmp[t] = v;
    __syncthreads();
    for (int off = 1; off < SCAN_BS; off <<= 1) {
        int x = (t >= off) ? tmp[t - off] : 0;
        __syncthreads();
        tmp[t] += x;
        __syncthreads();
    }
    if (i <= n) rowptr[i] = tmp[t] - v;
    if (t == SCAN_BS - 1) sums[b] = tmp[t];
}

__global__ void k_scan_sums(int* __restrict__ sums, int nb) {
    __shared__ int tmp[128];
    int t = threadIdx.x;
    int v = (t < nb) ? sums[t] : 0;
    tmp[t] = v;
    __syncthreads();
    for (int off = 1; off < 128; off <<= 1) {
        int x = (t >= off) ? tmp[t - off] : 0;
        __syncthreads();
        tmp[t] += x;
        __syncthreads();
    }
    if (t < nb) sums[t] = tmp[t] - v;
}

__global__ void k_scan_add(int* __restrict__ rowptr, const int* __restrict__ sums,
                           int* __restrict__ cursor, int n) {
    int i = blockIdx.x * blockDim.x + threadIdx.x;
    if (i <= n) {
        int v = rowptr[i] + sums[i >> 10];
        rowptr[i] = v;
        if (i < n) cursor[i] = v;
    }
}

__global__ void k_fill(const int* __restrict__ src, const int* __restrict__ dst,
                       int* __restrict__ cursor, int* __restrict__ srcs, int e) {
    int i = blockIdx.x * blockDim.x + threadIdx.x;
    if (i < e) {
        int d = __builtin_nontemporal_load(&dst[i]);
        int s = __builtin_nontemporal_load(&src[i]);
        int p = atomicAdd(&cursor[d], 1);
        __builtin_nontemporal_store(s, &srcs[p]);
    }
}

// ---------------- fused layer kernels ----------------

// layer 1 aggregate-first (4ch) + transform 3->32 + relu + transform 32->16, write h2n*dinv
__global__ __launch_bounds__(256) void g1k12(const int* __restrict__ rowptr,
                                             const int* __restrict__ srcs,
                                             const float4* __restrict__ xd,
                                             const float* __restrict__ dinv,
                                             const float* __restrict__ b1,
                                             const float* __restrict__ W1,
                                             const float* __restrict__ W2,
                                             float4* __restrict__ h2n, int n) {
    __shared__ float4 sW1[24];    // [3][32] as 3 rows x 8 quads
    __shared__ float4 sW2[128];   // [32][16] as 32 rows x 4 quads
    int t = threadIdx.x;
    if (t < 24) sW1[t] = ((const float4*)W1)[t];
    int u = t - 24;
    if (u >= 0 && u < 128) sW2[u] = ((const float4*)W2)[u];
    __syncthreads();
    int i = blockIdx.x * blockDim.x + t;
    if (i >= n) return;

    float4 acc = xd[i];                       // self loop
    int r0 = rowptr[i], r1 = rowptr[i + 1];
    for (int j = r0; j < r1; ++j) acc = f4add(acc, xd[srcs[j]]);

    float di = dinv[i];
    const float4* b14 = (const float4*)b1;
    float h[32];
#pragma unroll
    for (int q = 0; q < 8; ++q) {
        float4 s = {0, 0, 0, 0};
        s = f4fma(acc.x, sW1[q], s);
        s = f4fma(acc.y, sW1[8 + q], s);
        s = f4fma(acc.z, sW1[16 + q], s);
        float4 hv = f4relu(di, s, b14[q]);
        h[4 * q] = hv.x; h[4 * q + 1] = hv.y; h[4 * q + 2] = hv.z; h[4 * q + 3] = hv.w;
    }
    float4 o[4] = {{0,0,0,0},{0,0,0,0},{0,0,0,0},{0,0,0,0}};
#pragma unroll
    for (int k = 0; k < 32; ++k) {
        float hk = h[k];
#pragma unroll
        for (int q = 0; q < 4; ++q) o[q] = f4fma(hk, sW2[k * 4 + q], o[q]);
    }
#pragma unroll
    for (int q = 0; q < 4; ++q) {
        o[q].x *= di; o[q].y *= di; o[q].z *= di; o[q].w *= di;
        h2n[(size_t)i * 4 + q] = o[q];
    }
}

// layer 2 gather (16ch) + relu + transform 16->8, write h3n*dinv
__global__ __launch_bounds__(256) void g2(const int* __restrict__ rowptr,
                                          const int* __restrict__ srcs,
                                          const float4* __restrict__ h2n,
                                          const float* __restrict__ dinv,
                                          const float* __restrict__ b2,
                                          const float* __restrict__ W3,
                                          float4* __restrict__ h3n, int n) {
    __shared__ float4 sW3[32];    // [16][8] as 16 rows x 2 quads
    int t = threadIdx.x;
    if (t < 32) sW3[t] = ((const float4*)W3)[t];
    __syncthreads();
    int i = blockIdx.x * blockDim.x + t;
    if (i >= n) return;

    float4 a[4];
#pragma unroll
    for (int q = 0; q < 4; ++q) a[q] = h2n[(size_t)i * 4 + q];   // self loop
    int r0 = rowptr[i], r1 = rowptr[i + 1];
    for (int j = r0; j < r1; ++j) {
        int s = srcs[j];
#pragma unroll
        for (int q = 0; q < 4; ++q) a[q] = f4add(a[q], h2n[(size_t)s * 4 + q]);
    }
    float di = dinv[i];
    const float4* b24 = (const float4*)b2;
    float act[16];
#pragma unroll
    for (int q = 0; q < 4; ++q) {
        float4 v = f4relu(di, a[q], b24[q]);
        act[4 * q] = v.x; act[4 * q + 1] = v.y; act[4 * q + 2] = v.z; act[4 * q + 3] = v.w;
    }
    float4 o0 = {0,0,0,0}, o1 = {0,0,0,0};
#pragma unroll
    for (int k = 0; k < 16; ++k) {
        o0 = f4fma(act[k], sW3[k * 2], o0);
        o1 = f4fma(act[k], sW3[k * 2 + 1], o1);
    }
    o0.x *= di; o0.y *= di; o0.z *= di; o0.w *= di;
    o1.x *= di; o1.y *= di; o1.z *= di; o1.w *= di;
    h3n[(size_t)i * 2]     = o0;
    h3n[(size_t)i * 2 + 1] = o1;
}

// layer 3 gather (8ch) + relu + final 8->1 linear
__global__ __launch_bounds__(256) void g3(const int* __restrict__ rowptr,
                                          const int* __restrict__ srcs,
                                          const float4* __restrict__ h3n,
                                          const float* __restrict__ dinv,
                                          const float* __restrict__ b3,
                                          const float* __restrict__ Wf,
                                          const float* __restrict__ bf,
                                          float* __restrict__ out, int n) {
    int i = blockIdx.x * blockDim.x + threadIdx.x;
    if (i >= n) return;
    float4 a0 = h3n[(size_t)i * 2];
    float4 a1 = h3n[(size_t)i * 2 + 1];
    int r0 = rowptr[i], r1 = rowptr[i + 1];
    for (int j = r0; j < r1; ++j) {
        int s = srcs[j];
        a0 = f4add(a0, h3n[(size_t)s * 2]);
        a1 = f4add(a1, h3n[(size_t)s * 2 + 1]);
    }
    float di = dinv[i];
    float4 bb0 = ((const float4*)b3)[0], bb1 = ((const float4*)b3)[1];
    float4 w0 = ((const float4*)Wf)[0],  w1 = ((const float4*)Wf)[1];
    float4 r0v = f4relu(di, a0, bb0);
    float4 r1v = f4relu(di, a1, bb1);
    float s = bf[0];
    s += r0v.x * w0.x + r0v.y * w0.y + r0v.z * w0.z + r0v.w * w0.w;
    s += r1v.x * w1.x + r1v.y * w1.y + r1v.z * w1.z + r1v.w * w1.w;
    out[i] = s;
}

// ---------------- launch ----------------

extern "C" void kernel_launch(void* const* d_in, const int* in_sizes, int n_in,
                              void* d_out, int out_size, void* d_ws, size_t ws_size,
                              hipStream_t stream) {
    const float* x  = (const float*)d_in[0];
    const int*   ei = (const int*)d_in[1];
    const float* W1 = (const float*)d_in[2];
    const float* b1 = (const float*)d_in[3];
    const float* W2 = (const float*)d_in[4];
    const float* b2 = (const float*)d_in[5];
    const float* W3 = (const float*)d_in[6];
    const float* b3 = (const float*)d_in[7];
    const float* Wf = (const float*)d_in[8];
    const float* bf = (const float*)d_in[9];
    float* out = (float*)d_out;

    const int n = N_NODES;
    const int e = N_EDGES;
    const int* src = ei;
    const int* dst = ei + e;

    // workspace: xd[n]f4 | h2n[n*4]f4 | h3n[n*2]f4 | dinv[n] | srcs[e] | rowptr[n+1] | cursor[n] | hist[n] | sums[128]
    float4* xd   = (float4*)d_ws;
    float4* h2n  = xd + n;
    float4* h3n  = h2n + (size_t)n * 4;
    float*  dinv = (float*)(h3n + (size_t)n * 2);
    int*    srcs   = (int*)(dinv + n);
    int*    rowptr = srcs + e;
    int*    cursor = rowptr + (n + 1);
    int*    hist   = cursor + n;
    int*    sums   = hist + n;

    const int B = 256;
    const int nScanBlocks = cdiv(n, SCAN_BS);   // 98

    // ---- CSR build + dinv + xd ----
    k_zero_int<<<cdiv(n, B), B, 0, stream>>>(hist, n);
    k_hist<<<cdiv(e, B), B, 0, stream>>>(dst, hist, e);
    k_dinv_xd<<<cdiv(n, B), B, 0, stream>>>(hist, x, dinv, xd, n);
    k_scan_block<<<nScanBlocks, SCAN_BS, 0, stream>>>(hist, rowptr, sums, n);
    k_scan_sums<<<1, 128, 0, stream>>>(sums, nScanBlocks);
    k_scan_add<<<cdiv(n + 1, B), B, 0, stream>>>(rowptr, sums, cursor, n);
    k_fill<<<cdiv(e, B), B, 0, stream>>>(src, dst, cursor, srcs, e);

    // ---- fused layers ----
    g1k12<<<cdiv(n, B), B, 0, stream>>>(rowptr, srcs, xd, dinv, b1, W1, W2, h2n, n);
    g2<<<cdiv(n, B), B, 0, stream>>>(rowptr, srcs, h2n, dinv, b2, W3, h3n, n);
    g3<<<cdiv(n, B), B, 0, stream>>>(rowptr, srcs, h3n, dinv, b3, Wf, bf, out, n);
}